// Round 14
// baseline (58.480 us; speedup 1.0000x reference)
//
#include <hip/hip_runtime.h>

// VectorQuantiser R14: cut LDS-pipe traffic (the R13-identified currency).
// Wave owns 64 rows AND only half the codebook (code-split across the 2 waves
// of a block, argmin merged at the end). Chip-wide B ds_reads: 524K (R10) ->
// 262K; per-cfrag overhead amortized over 16 dists/lane. Block 128 thr, 64
// rows; grid 2048; LDS ~19.5KB (es dbuf 2x8KB of 32 shared codes + e2 + merge).
// launch_bounds(128,3): cap 170 > live ~144 (R11/R12 lesson: cap must exceed
// live-set or the allocator spills).
// prep: PRE-SWIZZLED f16-split codebook, e2 partials, embt affine.
// dist = e2[k] - 2*(xh.eh + xh.el + xl.eh); validated numerics since R3.

typedef _Float16 f16;
typedef _Float16 f16x8 __attribute__((ext_vector_type(8)));
typedef float    f32x4 __attribute__((ext_vector_type(4)));

#define NELEM0 8388608
#define FLTMAX 3.402823466e38f
// ws: [0,131072) ecvt_sw f16[512][128]; [131072,139264) e2p f32[4][512];
//     [139264,270336) embt f32[512][64]
#define WS_NEED 270336

// LDS read swizzle: f16 index = row*128 + (koff ^ ((row&7)<<3))
__device__ __forceinline__ int swz(int row, int koff) {
    return row * 128 + (koff ^ ((row & 7) << 3));
}

// prep: 8 blocks x 256 thr. block = (code-half)<<2 | d-chunk.
__global__ void prep_kernel(const float* __restrict__ emb, const float* __restrict__ meanp,
                            const float* __restrict__ sdp, f16* __restrict__ ecvt,
                            float* __restrict__ e2p, float* __restrict__ embt) {
    const int code = (blockIdx.x >> 2) * 256 + threadIdx.x;
    const int dc   = blockIdx.x & 3;                 // 16 d's per block
    const float mean = meanp[0];
    const float sd   = sdp[0];
    float s = 0.0f;
    #pragma unroll
    for (int j = 0; j < 16; ++j) {
        const int d = dc * 16 + j;
        float v = emb[d * 512 + code];               // coalesced across codes
        s = fmaf(v, v, s);
        f16 h = (f16)v;
        f16 l = (f16)(v - (float)h);
        const int gg = (d >> 3) ^ (code & 7);        // pre-apply inverse swizzle
        const int e  = d & 7;
        ecvt[code * 128 + gg * 8 + e]      = h;      // eh groups 0-7
        ecvt[code * 128 + 64 + gg * 8 + e] = l;      // el groups 8-15
        embt[code * 64 + d] = (v + mean) * sd;       // affine pre-applied
    }
    e2p[dc * 512 + code] = s;
}

__global__ __launch_bounds__(128, 3)
void vq_main(const float* __restrict__ x, const float* __restrict__ meanp,
             const float* __restrict__ sdp, const f16* __restrict__ ecvt,
             const float* __restrict__ e2p, const float* __restrict__ embt,
             float* __restrict__ out, float* __restrict__ outIdx)
{
    __shared__ __align__(16) f16 es[2][32 * 128];    // 2 x 8KB: 16 codes per wave each
    __shared__ float e2s[512];
    __shared__ float red_v[2][64];
    __shared__ int   red_i[2][64];
    __shared__ int   kbs[64];

    const int tid  = threadIdx.x;    // 0..127
    const int lane = tid & 63;
    const int w    = tid >> 6;       // 0/1: wave's codebook half
    const int lr   = lane & 15;
    const int lk   = lane >> 4;

    const int blk = blockIdx.x;      // 2048 = 32 b x 16 g x 4 cq
    const int cq  = blk & 3;
    const int g   = (blk >> 2) & 15;
    const int b   = blk >> 6;
    const int c0  = cq * 64;         // block's 64 rows

    const float sd   = sdp[0];
    const bool  sdz  = (sd == 0.0f);
    const float sinv = sdz ? 0.0f : (1.0f / sd);
    const float mean = meanp[0];

    const size_t xslab = (size_t)b * 262144 + (size_t)g * 16384;

    // ---- A fragments: 64 rows (same for both waves) from global into regs ----
    f16x8 ah[4][2], al[4][2];        // [set][ks: d 0-31 / 32-63]
    #pragma unroll
    for (int s = 0; s < 4; ++s) {
        const float* rp = x + xslab + c0 + s * 16 + lr;
        #pragma unroll
        for (int ks = 0; ks < 2; ++ks)
            #pragma unroll
            for (int j = 0; j < 8; ++j) {
                float v  = rp[(ks * 32 + lk * 8 + j) * 256];
                float sv = fmaf(v, sinv, -mean);
                f16 h = (f16)sv;
                ah[s][ks][j] = h;
                al[s][ks][j] = (f16)(sv - (float)h);
            }
    }

    // ---- e2 sums (fixed order: deterministic) ----
    #pragma unroll
    for (int i = 0; i < 4; ++i) {
        const int t = i * 128 + tid;
        e2s[t] = ((e2p[t] + e2p[512 + t]) + e2p[1024 + t]) + e2p[1536 + t];
    }

    // ---- prologue: stage chunk 0 (rows 0-15: codes 0-15; rows 16-31: 256-271) ----
    f16x8 pre[4];
    #pragma unroll
    for (int i = 0; i < 4; ++i) {
        const int u = i * 128 + tid;                 // 16B unit 0..511
        const f16* srcp = (i < 2)
            ? (ecvt + (size_t)u * 8)                 // region A: codes 0..15
            : (ecvt + 32768 + (size_t)(u - 256) * 8);// region B: codes 256..271
        pre[i] = *reinterpret_cast<const f16x8*>(srcp);
    }
    #pragma unroll
    for (int i = 0; i < 4; ++i)
        *reinterpret_cast<f16x8*>(&es[0][(i * 128 + tid) * 8]) = pre[i];
    __syncthreads();

    float bestv[16];
    int   besti[16];
    #pragma unroll
    for (int s = 0; s < 16; ++s) { bestv[s] = FLTMAX; besti[s] = 0; }

    // ---- main loop: 16 chunks; per chunk each wave does 1 cfrag (16 codes) ----
    for (int ch = 0; ch < 16; ++ch) {
        const int cur = ch & 1;
        const f16* eb = &es[cur][0];

        if (ch < 15) {                               // issue next-chunk loads EARLY
            const int cn = ch + 1;
            #pragma unroll
            for (int i = 0; i < 4; ++i) {
                const int u = i * 128 + tid;
                const f16* srcp = (i < 2)
                    ? (ecvt + (size_t)cn * 2048 + (size_t)u * 8)
                    : (ecvt + 32768 + (size_t)cn * 2048 + (size_t)(u - 256) * 8);
                pre[i] = *reinterpret_cast<const f16x8*>(srcp);
            }
        }

        {   // this wave's cfrag: LDS rows w*16 + lr
            const int rowB = w * 16 + lr;
            f16x8 bh0 = *reinterpret_cast<const f16x8*>(&eb[swz(rowB, lk * 8)]);
            f16x8 bh1 = *reinterpret_cast<const f16x8*>(&eb[swz(rowB, 32 + lk * 8)]);
            f16x8 bl0 = *reinterpret_cast<const f16x8*>(&eb[swz(rowB, 64 + lk * 8)]);
            f16x8 bl1 = *reinterpret_cast<const f16x8*>(&eb[swz(rowB, 96 + lk * 8)]);
            const int codeg = w * 256 + ch * 16 + lr;
            const float e2v = e2s[codeg];
            #pragma unroll
            for (int s = 0; s < 4; ++s) {
                f32x4 acc = (f32x4){0.f, 0.f, 0.f, 0.f};
                acc = __builtin_amdgcn_mfma_f32_16x16x32_f16(ah[s][0], bh0, acc, 0, 0, 0);
                acc = __builtin_amdgcn_mfma_f32_16x16x32_f16(ah[s][1], bh1, acc, 0, 0, 0);
                acc = __builtin_amdgcn_mfma_f32_16x16x32_f16(ah[s][0], bl0, acc, 0, 0, 0);
                acc = __builtin_amdgcn_mfma_f32_16x16x32_f16(ah[s][1], bl1, acc, 0, 0, 0);
                acc = __builtin_amdgcn_mfma_f32_16x16x32_f16(al[s][0], bh0, acc, 0, 0, 0);
                acc = __builtin_amdgcn_mfma_f32_16x16x32_f16(al[s][1], bh1, acc, 0, 0, 0);
                #pragma unroll
                for (int r = 0; r < 4; ++r) {
                    float vd = fmaf(-2.0f, acc[r], e2v);
                    const int si = s * 4 + r;
                    if (vd < bestv[si]) { bestv[si] = vd; besti[si] = codeg; }
                }
            }
        }

        if (ch < 15) {                               // write-late to other buffer
            #pragma unroll
            for (int i = 0; i < 4; ++i)
                *reinterpret_cast<f16x8*>(&es[cur ^ 1][(i * 128 + tid) * 8]) = pre[i];
        }
        __syncthreads();
    }

    // ---- in-wave argmin reduce over the 16 code-columns ----
    #pragma unroll
    for (int si = 0; si < 16; ++si) {
        float v = bestv[si]; int i = besti[si];
        #pragma unroll
        for (int m = 1; m < 16; m <<= 1) {
            float v2 = __shfl_xor(v, m, 64);
            int   i2 = __shfl_xor(i, m, 64);
            if (v2 < v || (v2 == v && i2 < i)) { v = v2; i = i2; }
        }
        bestv[si] = v; besti[si] = i;
    }
    if (lr == 0) {
        #pragma unroll
        for (int s = 0; s < 4; ++s)
            #pragma unroll
            for (int r = 0; r < 4; ++r) {
                const int row = s * 16 + lk * 4 + r;         // C/D layout row
                red_v[w][row] = bestv[s * 4 + r];
                red_i[w][row] = besti[s * 4 + r];
            }
    }
    __syncthreads();
    if (tid < 64) {
        const float v0 = red_v[0][tid], v1 = red_v[1][tid];
        const int   i0 = red_i[0][tid], i1 = red_i[1][tid];
        kbs[tid] = (v1 < v0) ? i1 : i0;   // wave0 codes < wave1: tie keeps i0
    }
    __syncthreads();

    // ---- epilogue: stream embt row, coalesced d-major stores ----
    {
        const int c_ = tid & 63;
        const int dh = tid >> 6;                     // d half (32 each)
        const int k  = kbs[c_];
        const float* qrow = embt + k * 64 + dh * 32; // L2-resident
        float* op = out + xslab + (size_t)(dh * 32) * 256 + c0 + c_;
        #pragma unroll
        for (int q4 = 0; q4 < 8; ++q4) {
            f32x4 qq = *reinterpret_cast<const f32x4*>(&qrow[q4 * 4]);
            #pragma unroll
            for (int j = 0; j < 4; ++j)
                op[(q4 * 4 + j) * 256] = qq[j];
        }
    }
    if (tid < 64)
        outIdx[(size_t)(b * 256 + c0 + tid) * 16 + g] = (float)kbs[tid];
}

// ---------------- fallback (ws too small): R5-style self-contained -------------
__global__ __launch_bounds__(512, 2)
void vq_fallback(const float* __restrict__ x, const float* __restrict__ meanp,
                 const float* __restrict__ sdp, const float* __restrict__ emb,
                 float* __restrict__ out, float* __restrict__ outIdx)
{
    __shared__ __align__(16) f16 xa[128 * 128];
    __shared__ __align__(16) f16 es2[128 * 128];
    __shared__ float e2s[512];
    __shared__ float red_v[4][128];
    __shared__ int   red_i[4][128];
    __shared__ int   kb[128];

    const int tid  = threadIdx.x;
    const int lane = tid & 63;
    const int wid  = tid >> 6;
    const int wr   = wid >> 2;
    const int wc   = wid & 3;
    const int lr   = lane & 15;
    const int lk   = lane >> 4;

    const int blk   = blockIdx.x;
    const int chalf = blk & 1;
    const int g     = (blk >> 1) & 15;
    const int b     = blk >> 5;

    const float mean = meanp[0];
    const float sd   = sdp[0];
    const bool  sdz  = (sd == 0.0f);
    const float safe = sdz ? 1.0f : sd;

    const int xbase = b * 262144 + g * 16384 + chalf * 128;

    {
        const int c_ = tid & 127;
        const int dq = tid >> 7;
        const float* src = x + xbase + c_;
        #pragma unroll
        for (int jv = 0; jv < 2; ++jv) {
            f16x8 hi, lo;
            #pragma unroll
            for (int e = 0; e < 8; ++e) {
                int d = dq * 16 + jv * 8 + e;
                float v = src[d * 256];
                float s = (sdz ? 0.0f : v / safe) - mean;
                f16 h = (f16)s;
                hi[e] = h;
                lo[e] = (f16)(s - (float)h);
            }
            *reinterpret_cast<f16x8*>(&xa[swz(c_, dq * 16 + jv * 8)])      = hi;
            *reinterpret_cast<f16x8*>(&xa[swz(c_, 64 + dq * 16 + jv * 8)]) = lo;
        }
    }
    {
        float s = 0.0f;
        for (int d = 0; d < 64; ++d) {
            float v = emb[d * 512 + tid];
            s = fmaf(v, v, s);
        }
        e2s[tid] = s;
    }

    float bestv[16];
    int   besti[16];
    #pragma unroll
    for (int s = 0; s < 16; ++s) { bestv[s] = FLTMAX; besti[s] = 0; }

    for (int ch = 0; ch < 4; ++ch) {
        __syncthreads();
        {
            const int cl = tid & 127;
            const int dq = tid >> 7;
            const float* srcE = emb + ch * 128 + cl;
            #pragma unroll
            for (int jv = 0; jv < 2; ++jv) {
                f16x8 hi, lo;
                #pragma unroll
                for (int e = 0; e < 8; ++e) {
                    int d = dq * 16 + jv * 8 + e;
                    float v = srcE[d * 512];
                    f16 h = (f16)v;
                    hi[e] = h;
                    lo[e] = (f16)(v - (float)h);
                }
                *reinterpret_cast<f16x8*>(&es2[swz(cl, dq * 16 + jv * 8)])      = hi;
                *reinterpret_cast<f16x8*>(&es2[swz(cl, 64 + dq * 16 + jv * 8)]) = lo;
            }
        }
        __syncthreads();

        f32x4 acc[4][2];
        #pragma unroll
        for (int fi = 0; fi < 4; ++fi)
            #pragma unroll
            for (int fj = 0; fj < 2; ++fj)
                acc[fi][fj] = (f32x4){0.f, 0.f, 0.f, 0.f};

        #pragma unroll
        for (int t = 0; t < 3; ++t) {
            const int ah2 = (t == 2) ? 1 : 0;
            const int eh2 = (t == 1) ? 1 : 0;
            #pragma unroll
            for (int dh2 = 0; dh2 < 2; ++dh2) {
                const int kB = eh2 * 64 + dh2 * 32 + lk * 8;
                const int kA = ah2 * 64 + dh2 * 32 + lk * 8;
                f16x8 bf[2], af[4];
                #pragma unroll
                for (int fj = 0; fj < 2; ++fj)
                    bf[fj] = *reinterpret_cast<const f16x8*>(
                        &es2[swz(wc * 32 + fj * 16 + lr, kB)]);
                #pragma unroll
                for (int fi = 0; fi < 4; ++fi)
                    af[fi] = *reinterpret_cast<const f16x8*>(
                        &xa[swz(wr * 64 + fi * 16 + lr, kA)]);
                #pragma unroll
                for (int fi = 0; fi < 4; ++fi)
                    #pragma unroll
                    for (int fj = 0; fj < 2; ++fj)
                        acc[fi][fj] = __builtin_amdgcn_mfma_f32_16x16x32_f16(
                            af[fi], bf[fj], acc[fi][fj], 0, 0, 0);
            }
        }

        #pragma unroll
        for (int fj = 0; fj < 2; ++fj) {
            const int codeg = ch * 128 + wc * 32 + fj * 16 + lr;
            const float e2v = e2s[codeg];
            #pragma unroll
            for (int fi = 0; fi < 4; ++fi)
                #pragma unroll
                for (int r = 0; r < 4; ++r) {
                    float vd = fmaf(-2.0f, acc[fi][fj][r], e2v);
                    const int s = fi * 4 + r;
                    if (vd < bestv[s]) { bestv[s] = vd; besti[s] = codeg; }
                }
        }
    }

    #pragma unroll
    for (int s = 0; s < 16; ++s) {
        float v = bestv[s]; int i = besti[s];
        #pragma unroll
        for (int m = 1; m < 16; m <<= 1) {
            float v2 = __shfl_xor(v, m, 64);
            int   i2 = __shfl_xor(i, m, 64);
            if (v2 < v || (v2 == v && i2 < i)) { v = v2; i = i2; }
        }
        bestv[s] = v; besti[s] = i;
    }
    if (lr == 0) {
        #pragma unroll
        for (int fi = 0; fi < 4; ++fi)
            #pragma unroll
            for (int r = 0; r < 4; ++r) {
                int row = wr * 64 + fi * 16 + lk * 4 + r;
                red_v[wc][row] = bestv[fi * 4 + r];
                red_i[wc][row] = besti[fi * 4 + r];
            }
    }
    __syncthreads();
    if (tid < 128) {
        float bv = red_v[0][tid]; int bi = red_i[0][tid];
        #pragma unroll
        for (int w2 = 1; w2 < 4; ++w2) {
            float v = red_v[w2][tid]; int i = red_i[w2][tid];
            if (v < bv || (v == bv && i < bi)) { bv = v; bi = i; }
        }
        kb[tid] = bi;
    }
    __syncthreads();

    float* out_ = out + xbase;
    #pragma unroll 4
    for (int i = 0; i < 16; ++i) {
        int lin = i * 512 + tid;
        int c_  = lin & 127;
        int d   = lin >> 7;
        float q = emb[d * 512 + kb[c_]];
        out_[d * 256 + c_] = (q + mean) * sd;
    }
    if (tid < 128) {
        int n = (b * 256 + chalf * 128 + tid) * 16 + g;
        outIdx[n] = (float)kb[tid];
    }
}

extern "C" void kernel_launch(void* const* d_in, const int* in_sizes, int n_in,
                              void* d_out, int out_size, void* d_ws, size_t ws_size,
                              hipStream_t stream) {
    const float* x    = (const float*)d_in[0];
    const float* mean = (const float*)d_in[1];
    const float* sd   = (const float*)d_in[2];
    const float* emb  = (const float*)d_in[3];
    float* out    = (float*)d_out;
    float* outIdx = out + NELEM0;

    if (ws_size >= (size_t)WS_NEED) {
        f16*   ecvt = (f16*)d_ws;
        float* e2p  = (float*)((char*)d_ws + 131072);
        float* embt = (float*)((char*)d_ws + 139264);
        prep_kernel<<<dim3(8), dim3(256), 0, stream>>>(emb, mean, sd, ecvt, e2p, embt);
        vq_main<<<dim3(2048), dim3(128), 0, stream>>>(x, mean, sd, ecvt, e2p, embt, out, outIdx);
    } else {
        vq_fallback<<<dim3(1024), dim3(512), 0, stream>>>(x, mean, sd, emb, out, outIdx);
    }
}

// Round 15
// 46.652 us; speedup vs baseline: 1.2535x; 1.2535x over previous
//
#include <hip/hip_runtime.h>

// VectorQuantiser R15: R10 (best, 45.5us) + global_load_lds staging + split chains.
// R10 structure: 1024 blocks x 256 thr (4 waves), 128 rows/block (32/wave),
// 8 chunks x 64 codes, es dbuf 2x16KB, LDS ~35KB -> 4 blocks/CU.
// R15 changes: (1) es staged via __builtin_amdgcn_global_load_lds width=16
// (DMA, no VGPR round-trip, no ds_write VALU; linear LDS dest + pre-swizzled
// global source per rule #21); (2) 6-deep MFMA chain -> 2x3 + add.
// dist = e2[k] - 2*(xh.eh + xh.el + xl.eh); numerics validated R3-R14.

typedef _Float16 f16;
typedef _Float16 f16x8 __attribute__((ext_vector_type(8)));
typedef float    f32x4 __attribute__((ext_vector_type(4)));

#define NELEM0 8388608
#define FLTMAX 3.402823466e38f
// ws: [0,131072) ecvt_sw f16[512][128]; [131072,139264) e2p f32[4][512];
//     [139264,270336) embt f32[512][64]
#define WS_NEED 270336

__device__ __forceinline__ void gload_lds16(const void* g, void* l) {
    __builtin_amdgcn_global_load_lds(
        (const __attribute__((address_space(1))) void*)g,
        (__attribute__((address_space(3))) void*)l, 16, 0, 0);
}

// LDS read swizzle: f16 index = row*128 + (koff ^ ((row&7)<<3))
__device__ __forceinline__ int swz(int row, int koff) {
    return row * 128 + (koff ^ ((row & 7) << 3));
}

// prep: 8 blocks x 256 thr. block = (code-half)<<2 | d-chunk.
__global__ void prep_kernel(const float* __restrict__ emb, const float* __restrict__ meanp,
                            const float* __restrict__ sdp, f16* __restrict__ ecvt,
                            float* __restrict__ e2p, float* __restrict__ embt) {
    const int code = (blockIdx.x >> 2) * 256 + threadIdx.x;
    const int dc   = blockIdx.x & 3;                 // 16 d's per block
    const float mean = meanp[0];
    const float sd   = sdp[0];
    float s = 0.0f;
    #pragma unroll
    for (int j = 0; j < 16; ++j) {
        const int d = dc * 16 + j;
        float v = emb[d * 512 + code];               // coalesced across codes
        s = fmaf(v, v, s);
        f16 h = (f16)v;
        f16 l = (f16)(v - (float)h);
        const int gg = (d >> 3) ^ (code & 7);        // pre-apply inverse swizzle
        const int e  = d & 7;
        ecvt[code * 128 + gg * 8 + e]      = h;      // eh groups 0-7
        ecvt[code * 128 + 64 + gg * 8 + e] = l;      // el groups 8-15
        embt[code * 64 + d] = (v + mean) * sd;       // affine pre-applied
    }
    e2p[dc * 512 + code] = s;
}

__global__ __launch_bounds__(256, 4)
void vq_main(const float* __restrict__ x, const float* __restrict__ meanp,
             const float* __restrict__ sdp, const f16* __restrict__ ecvt,
             const float* __restrict__ e2p, const float* __restrict__ embt,
             float* __restrict__ out, float* __restrict__ outIdx)
{
    __shared__ __align__(16) f16 es[2][64 * 128];    // 2 x 16 KB, linear copies
    __shared__ float e2s[512];
    __shared__ int   kbs[128];

    const int tid  = threadIdx.x;
    const int lane = tid & 63;
    const int wid  = tid >> 6;       // 0..3; wave owns 32 rows
    const int lr   = lane & 15;
    const int lk   = lane >> 4;

    const int blk   = blockIdx.x;    // 1024 = 32 b x 16 g x 2 chalf
    const int chalf = blk & 1;
    const int g     = (blk >> 1) & 15;
    const int b     = blk >> 5;

    const float sd   = sdp[0];
    const bool  sdz  = (sd == 0.0f);
    const float sinv = sdz ? 0.0f : (1.0f / sd);
    const float mean = meanp[0];

    const size_t xslab = (size_t)b * 262144 + (size_t)g * 16384;
    const int c0 = chalf * 128 + wid * 32;           // wave's first row (global c)

    // ---- prologue: DMA chunk 0 into es[0] (contiguous, linear LDS dest) ----
    #pragma unroll
    for (int i = 0; i < 4; ++i)
        gload_lds16(ecvt + i * 2048 + tid * 8, &es[0][i * 2048 + tid * 8]);

    // ---- A fragments: 32 rows/wave straight from global into regs ----
    f16x8 ah[2][2], al[2][2];        // [set][ks: d 0-31 / 32-63]
    #pragma unroll
    for (int s = 0; s < 2; ++s) {
        const float* rp = x + xslab + c0 + s * 16 + lr;
        #pragma unroll
        for (int ks = 0; ks < 2; ++ks)
            #pragma unroll
            for (int j = 0; j < 8; ++j) {
                float v  = rp[(ks * 32 + lk * 8 + j) * 256];
                float sv = fmaf(v, sinv, -mean);
                f16 h = (f16)sv;
                ah[s][ks][j] = h;
                al[s][ks][j] = (f16)(sv - (float)h);
            }
    }

    // ---- e2 sums (fixed order: deterministic) ----
    {
        e2s[tid] = ((e2p[tid] + e2p[512 + tid]) + e2p[1024 + tid]) + e2p[1536 + tid];
        const int t2 = 256 + tid;
        e2s[t2]  = ((e2p[t2]  + e2p[512 + t2])  + e2p[1024 + t2])  + e2p[1536 + t2];
    }
    __syncthreads();

    float bestv[8];
    int   besti[8];
    #pragma unroll
    for (int s = 0; s < 8; ++s) { bestv[s] = FLTMAX; besti[s] = 0; }

    // ---- main loop: 8 chunks x 64 codes; DMA next chunk at chunk top ----
    for (int ch = 0; ch < 8; ++ch) {
        const int cur = ch & 1;
        const f16* eb = &es[cur][0];

        if (ch < 7) {                                // DMA next chunk into freed buffer
            #pragma unroll
            for (int i = 0; i < 4; ++i)
                gload_lds16(ecvt + (ch + 1) * 8192 + i * 2048 + tid * 8,
                            &es[cur ^ 1][i * 2048 + tid * 8]);
        }

        #pragma unroll
        for (int cf = 0; cf < 4; ++cf) {             // 16 codes per cfrag
            const int rowB = cf * 16 + lr;
            f16x8 bh0 = *reinterpret_cast<const f16x8*>(&eb[swz(rowB, lk * 8)]);
            f16x8 bh1 = *reinterpret_cast<const f16x8*>(&eb[swz(rowB, 32 + lk * 8)]);
            f16x8 bl0 = *reinterpret_cast<const f16x8*>(&eb[swz(rowB, 64 + lk * 8)]);
            f16x8 bl1 = *reinterpret_cast<const f16x8*>(&eb[swz(rowB, 96 + lk * 8)]);
            const int codeg = ch * 64 + cf * 16 + lr;
            const float e2v = e2s[codeg];
            #pragma unroll
            for (int s = 0; s < 2; ++s) {
                f32x4 a0 = (f32x4){0.f, 0.f, 0.f, 0.f};
                f32x4 a1 = (f32x4){0.f, 0.f, 0.f, 0.f};
                a0 = __builtin_amdgcn_mfma_f32_16x16x32_f16(ah[s][0], bh0, a0, 0, 0, 0);
                a0 = __builtin_amdgcn_mfma_f32_16x16x32_f16(ah[s][1], bh1, a0, 0, 0, 0);
                a0 = __builtin_amdgcn_mfma_f32_16x16x32_f16(ah[s][0], bl0, a0, 0, 0, 0);
                a1 = __builtin_amdgcn_mfma_f32_16x16x32_f16(ah[s][1], bl1, a1, 0, 0, 0);
                a1 = __builtin_amdgcn_mfma_f32_16x16x32_f16(al[s][0], bh0, a1, 0, 0, 0);
                a1 = __builtin_amdgcn_mfma_f32_16x16x32_f16(al[s][1], bh1, a1, 0, 0, 0);
                #pragma unroll
                for (int r = 0; r < 4; ++r) {
                    float vd = fmaf(-2.0f, a0[r] + a1[r], e2v);
                    const int si = s * 4 + r;
                    if (vd < bestv[si]) { bestv[si] = vd; besti[si] = codeg; }
                }
            }
        }

        __syncthreads();   // drains DMA (vmcnt) + protects buffer swap
    }

    // ---- in-wave argmin reduce over the 16 code-columns ----
    #pragma unroll
    for (int si = 0; si < 8; ++si) {
        float v = bestv[si]; int i = besti[si];
        #pragma unroll
        for (int m = 1; m < 16; m <<= 1) {
            float v2 = __shfl_xor(v, m, 64);
            int   i2 = __shfl_xor(i, m, 64);
            if (v2 < v || (v2 == v && i2 < i)) { v = v2; i = i2; }
        }
        bestv[si] = v; besti[si] = i;
    }
    if (lr == 0) {
        #pragma unroll
        for (int s = 0; s < 2; ++s)
            #pragma unroll
            for (int r = 0; r < 4; ++r)
                kbs[wid * 32 + s * 16 + lk * 4 + r] = besti[s * 4 + r];  // C/D row map
    }
    __syncthreads();

    // ---- epilogue: scatter-read embt row, coalesced d-major stores ----
    {
        const int c_ = tid & 127;
        const int dh = tid >> 7;                     // d half (32 each)
        const int k  = kbs[c_];
        const float* qrow = embt + k * 64 + dh * 32; // L2-resident
        float* op = out + xslab + (size_t)(dh * 32) * 256 + chalf * 128 + c_;
        #pragma unroll
        for (int q4 = 0; q4 < 8; ++q4) {
            f32x4 qq = *reinterpret_cast<const f32x4*>(&qrow[q4 * 4]);
            #pragma unroll
            for (int j = 0; j < 4; ++j)
                op[(q4 * 4 + j) * 256] = qq[j];
        }
    }
    if (tid < 128)
        outIdx[(size_t)(b * 256 + chalf * 128 + tid) * 16 + g] = (float)kbs[tid];
}

// ---------------- fallback (ws too small): R5-style self-contained -------------
__global__ __launch_bounds__(512, 2)
void vq_fallback(const float* __restrict__ x, const float* __restrict__ meanp,
                 const float* __restrict__ sdp, const float* __restrict__ emb,
                 float* __restrict__ out, float* __restrict__ outIdx)
{
    __shared__ __align__(16) f16 xa[128 * 128];
    __shared__ __align__(16) f16 es2[128 * 128];
    __shared__ float e2s[512];
    __shared__ float red_v[4][128];
    __shared__ int   red_i[4][128];
    __shared__ int   kb[128];

    const int tid  = threadIdx.x;
    const int lane = tid & 63;
    const int wid  = tid >> 6;
    const int wr   = wid >> 2;
    const int wc   = wid & 3;
    const int lr   = lane & 15;
    const int lk   = lane >> 4;

    const int blk   = blockIdx.x;
    const int chalf = blk & 1;
    const int g     = (blk >> 1) & 15;
    const int b     = blk >> 5;

    const float mean = meanp[0];
    const float sd   = sdp[0];
    const bool  sdz  = (sd == 0.0f);
    const float safe = sdz ? 1.0f : sd;

    const int xbase = b * 262144 + g * 16384 + chalf * 128;

    {
        const int c_ = tid & 127;
        const int dq = tid >> 7;
        const float* src = x + xbase + c_;
        #pragma unroll
        for (int jv = 0; jv < 2; ++jv) {
            f16x8 hi, lo;
            #pragma unroll
            for (int e = 0; e < 8; ++e) {
                int d = dq * 16 + jv * 8 + e;
                float v = src[d * 256];
                float s = (sdz ? 0.0f : v / safe) - mean;
                f16 h = (f16)s;
                hi[e] = h;
                lo[e] = (f16)(s - (float)h);
            }
            *reinterpret_cast<f16x8*>(&xa[swz(c_, dq * 16 + jv * 8)])      = hi;
            *reinterpret_cast<f16x8*>(&xa[swz(c_, 64 + dq * 16 + jv * 8)]) = lo;
        }
    }
    {
        float s = 0.0f;
        for (int d = 0; d < 64; ++d) {
            float v = emb[d * 512 + tid];
            s = fmaf(v, v, s);
        }
        e2s[tid] = s;
    }

    float bestv[16];
    int   besti[16];
    #pragma unroll
    for (int s = 0; s < 16; ++s) { bestv[s] = FLTMAX; besti[s] = 0; }

    for (int ch = 0; ch < 4; ++ch) {
        __syncthreads();
        {
            const int cl = tid & 127;
            const int dq = tid >> 7;
            const float* srcE = emb + ch * 128 + cl;
            #pragma unroll
            for (int jv = 0; jv < 2; ++jv) {
                f16x8 hi, lo;
                #pragma unroll
                for (int e = 0; e < 8; ++e) {
                    int d = dq * 16 + jv * 8 + e;
                    float v = srcE[d * 512];
                    f16 h = (f16)v;
                    hi[e] = h;
                    lo[e] = (f16)(v - (float)h);
                }
                *reinterpret_cast<f16x8*>(&es2[swz(cl, dq * 16 + jv * 8)])      = hi;
                *reinterpret_cast<f16x8*>(&es2[swz(cl, 64 + dq * 16 + jv * 8)]) = lo;
            }
        }
        __syncthreads();

        f32x4 acc[4][2];
        #pragma unroll
        for (int fi = 0; fi < 4; ++fi)
            #pragma unroll
            for (int fj = 0; fj < 2; ++fj)
                acc[fi][fj] = (f32x4){0.f, 0.f, 0.f, 0.f};

        #pragma unroll
        for (int t = 0; t < 3; ++t) {
            const int ah2 = (t == 2) ? 1 : 0;
            const int eh2 = (t == 1) ? 1 : 0;
            #pragma unroll
            for (int dh2 = 0; dh2 < 2; ++dh2) {
                const int kB = eh2 * 64 + dh2 * 32 + lk * 8;
                const int kA = ah2 * 64 + dh2 * 32 + lk * 8;
                f16x8 bf[2], af[4];
                #pragma unroll
                for (int fj = 0; fj < 2; ++fj)
                    bf[fj] = *reinterpret_cast<const f16x8*>(
                        &es2[swz(wc * 32 + fj * 16 + lr, kB)]);
                #pragma unroll
                for (int fi = 0; fi < 4; ++fi)
                    af[fi] = *reinterpret_cast<const f16x8*>(
                        &xa[swz(wr * 64 + fi * 16 + lr, kA)]);
                #pragma unroll
                for (int fi = 0; fi < 4; ++fi)
                    #pragma unroll
                    for (int fj = 0; fj < 2; ++fj)
                        acc[fi][fj] = __builtin_amdgcn_mfma_f32_16x16x32_f16(
                            af[fi], bf[fj], acc[fi][fj], 0, 0, 0);
            }
        }

        #pragma unroll
        for (int fj = 0; fj < 2; ++fj) {
            const int codeg = ch * 128 + wc * 32 + fj * 16 + lr;
            const float e2v = e2s[codeg];
            #pragma unroll
            for (int fi = 0; fi < 4; ++fi)
                #pragma unroll
                for (int r = 0; r < 4; ++r) {
                    float vd = fmaf(-2.0f, acc[fi][fj][r], e2v);
                    const int s = fi * 4 + r;
                    if (vd < bestv[s]) { bestv[s] = vd; besti[s] = codeg; }
                }
        }
    }

    #pragma unroll
    for (int s = 0; s < 16; ++s) {
        float v = bestv[s]; int i = besti[s];
        #pragma unroll
        for (int m = 1; m < 16; m <<= 1) {
            float v2 = __shfl_xor(v, m, 64);
            int   i2 = __shfl_xor(i, m, 64);
            if (v2 < v || (v2 == v && i2 < i)) { v = v2; i = i2; }
        }
        bestv[s] = v; besti[s] = i;
    }
    if (lr == 0) {
        #pragma unroll
        for (int fi = 0; fi < 4; ++fi)
            #pragma unroll
            for (int r = 0; r < 4; ++r) {
                int row = wr * 64 + fi * 16 + lk * 4 + r;
                red_v[wc][row] = bestv[fi * 4 + r];
                red_i[wc][row] = besti[fi * 4 + r];
            }
    }
    __syncthreads();
    if (tid < 128) {
        float bv = red_v[0][tid]; int bi = red_i[0][tid];
        #pragma unroll
        for (int w2 = 1; w2 < 4; ++w2) {
            float v = red_v[w2][tid]; int i = red_i[w2][tid];
            if (v < bv || (v == bv && i < bi)) { bv = v; bi = i; }
        }
        kb[tid] = bi;
    }
    __syncthreads();

    float* out_ = out + xbase;
    #pragma unroll 4
    for (int i = 0; i < 16; ++i) {
        int lin = i * 512 + tid;
        int c_  = lin & 127;
        int d   = lin >> 7;
        float q = emb[d * 512 + kb[c_]];
        out_[d * 256 + c_] = (q + mean) * sd;
    }
    if (tid < 128) {
        int n = (b * 256 + chalf * 128 + tid) * 16 + g;
        outIdx[n] = (float)kb[tid];
    }
}

extern "C" void kernel_launch(void* const* d_in, const int* in_sizes, int n_in,
                              void* d_out, int out_size, void* d_ws, size_t ws_size,
                              hipStream_t stream) {
    const float* x    = (const float*)d_in[0];
    const float* mean = (const float*)d_in[1];
    const float* sd   = (const float*)d_in[2];
    const float* emb  = (const float*)d_in[3];
    float* out    = (float*)d_out;
    float* outIdx = out + NELEM0;

    if (ws_size >= (size_t)WS_NEED) {
        f16*   ecvt = (f16*)d_ws;
        float* e2p  = (float*)((char*)d_ws + 131072);
        float* embt = (float*)((char*)d_ws + 139264);
        prep_kernel<<<dim3(8), dim3(256), 0, stream>>>(emb, mean, sd, ecvt, e2p, embt);
        vq_main<<<dim3(1024), dim3(256), 0, stream>>>(x, mean, sd, ecvt, e2p, embt, out, outIdx);
    } else {
        vq_fallback<<<dim3(1024), dim3(512), 0, stream>>>(x, mean, sd, emb, out, outIdx);
    }
}

// Round 16
// 46.645 us; speedup vs baseline: 1.2537x; 1.0002x over previous
//
#include <hip/hip_runtime.h>

// VectorQuantiser R16: R10 structure + T4 counted-vmcnt distance-2 DMA pipeline.
// 1024 blocks x 256 thr (4 waves), 128 rows/block (32/wave); 16 chunks x 32
// codes; es = 4 x 8KB ring (DMA global_load_lds w16, linear dest, PRE-SWIZZLED
// source); per-chunk: issue ch+2, compute ch, then s_waitcnt vmcnt(2) (never 0
// mid-loop) + raw s_barrier (+sched_barrier fences, rule 18). LDS 34.8KB ->
// 4 blocks/CU. dist = e2[k] - 2*(xh.eh + xh.el + xl.eh); numerics = R10/R13.

typedef _Float16 f16;
typedef _Float16 f16x8 __attribute__((ext_vector_type(8)));
typedef float    f32x4 __attribute__((ext_vector_type(4)));

#define NELEM0 8388608
#define FLTMAX 3.402823466e38f
// ws: [0,131072) ecvt_sw f16[512][128]; [131072,139264) e2p f32[4][512];
//     [139264,270336) embt f32[512][64]
#define WS_NEED 270336

__device__ __forceinline__ void gload_lds16(const void* g, void* l) {
    __builtin_amdgcn_global_load_lds(
        (const __attribute__((address_space(1))) void*)g,
        (__attribute__((address_space(3))) void*)l, 16, 0, 0);
}

// LDS read swizzle: f16 index = row*128 + (koff ^ ((row&7)<<3))
__device__ __forceinline__ int swz(int row, int koff) {
    return row * 128 + (koff ^ ((row & 7) << 3));
}

// prep: 8 blocks x 256 thr. block = (code-half)<<2 | d-chunk.
__global__ void prep_kernel(const float* __restrict__ emb, const float* __restrict__ meanp,
                            const float* __restrict__ sdp, f16* __restrict__ ecvt,
                            float* __restrict__ e2p, float* __restrict__ embt) {
    const int code = (blockIdx.x >> 2) * 256 + threadIdx.x;
    const int dc   = blockIdx.x & 3;                 // 16 d's per block
    const float mean = meanp[0];
    const float sd   = sdp[0];
    float s = 0.0f;
    #pragma unroll
    for (int j = 0; j < 16; ++j) {
        const int d = dc * 16 + j;
        float v = emb[d * 512 + code];               // coalesced across codes
        s = fmaf(v, v, s);
        f16 h = (f16)v;
        f16 l = (f16)(v - (float)h);
        const int gg = (d >> 3) ^ (code & 7);        // pre-apply inverse swizzle
        const int e  = d & 7;
        ecvt[code * 128 + gg * 8 + e]      = h;      // eh groups 0-7
        ecvt[code * 128 + 64 + gg * 8 + e] = l;      // el groups 8-15
        embt[code * 64 + d] = (v + mean) * sd;       // affine pre-applied
    }
    e2p[dc * 512 + code] = s;
}

__global__ __launch_bounds__(256, 4)
void vq_main(const float* __restrict__ x, const float* __restrict__ meanp,
             const float* __restrict__ sdp, const f16* __restrict__ ecvt,
             const float* __restrict__ e2p, const float* __restrict__ embt,
             float* __restrict__ out, float* __restrict__ outIdx)
{
    __shared__ __align__(16) f16 es[4][32 * 128];    // 4 x 8 KB ring
    __shared__ float e2s[512];
    __shared__ int   kbs[128];

    const int tid  = threadIdx.x;
    const int lane = tid & 63;
    const int wid  = tid >> 6;       // 0..3; wave owns 32 rows
    const int lr   = lane & 15;
    const int lk   = lane >> 4;

    const int blk   = blockIdx.x;    // 1024 = 32 b x 16 g x 2 chalf
    const int chalf = blk & 1;
    const int g     = (blk >> 1) & 15;
    const int b     = blk >> 5;

    const float sd   = sdp[0];
    const bool  sdz  = (sd == 0.0f);
    const float sinv = sdz ? 0.0f : (1.0f / sd);
    const float mean = meanp[0];

    const size_t xslab = (size_t)b * 262144 + (size_t)g * 16384;
    const int c0 = chalf * 128 + wid * 32;           // wave's first row (global c)

    // ---- prologue: DMA chunks 0 and 1 into ring slots 0,1 ----
    #pragma unroll
    for (int i = 0; i < 2; ++i)
        gload_lds16(ecvt + i * 2048 + tid * 8, &es[0][i * 2048 + tid * 8]);
    #pragma unroll
    for (int i = 0; i < 2; ++i)
        gload_lds16(ecvt + 4096 + i * 2048 + tid * 8, &es[1][i * 2048 + tid * 8]);

    // ---- A fragments: 32 rows/wave straight from global into regs ----
    f16x8 ah[2][2], al[2][2];        // [set][ks: d 0-31 / 32-63]
    #pragma unroll
    for (int s = 0; s < 2; ++s) {
        const float* rp = x + xslab + c0 + s * 16 + lr;
        #pragma unroll
        for (int ks = 0; ks < 2; ++ks)
            #pragma unroll
            for (int j = 0; j < 8; ++j) {
                float v  = rp[(ks * 32 + lk * 8 + j) * 256];
                float sv = fmaf(v, sinv, -mean);
                f16 h = (f16)sv;
                ah[s][ks][j] = h;
                al[s][ks][j] = (f16)(sv - (float)h);
            }
    }

    // ---- e2 sums (fixed order: deterministic) ----
    {
        e2s[tid] = ((e2p[tid] + e2p[512 + tid]) + e2p[1024 + tid]) + e2p[1536 + tid];
        const int t2 = 256 + tid;
        e2s[t2]  = ((e2p[t2]  + e2p[512 + t2])  + e2p[1024 + t2])  + e2p[1536 + t2];
    }

    // prologue barrier: chunk0 landed (allow chunk1's 2 loads in flight),
    // e2s ds_writes visible (lgkmcnt 0)
    asm volatile("s_waitcnt vmcnt(2) lgkmcnt(0)" ::: "memory");
    __builtin_amdgcn_sched_barrier(0);
    __builtin_amdgcn_s_barrier();
    __builtin_amdgcn_sched_barrier(0);

    float bestv[8];
    int   besti[8];
    #pragma unroll
    for (int s = 0; s < 8; ++s) { bestv[s] = FLTMAX; besti[s] = 0; }

    // ---- main loop: 16 chunks x 32 codes, distance-2 DMA, counted vmcnt ----
    for (int ch = 0; ch < 16; ++ch) {
        const int cur = ch & 3;
        const f16* eb = &es[cur][0];

        if (ch < 14) {                               // DMA ch+2 into ring slot
            f16* dst = &es[(ch + 2) & 3][0];
            #pragma unroll
            for (int i = 0; i < 2; ++i)
                gload_lds16(ecvt + (ch + 2) * 4096 + i * 2048 + tid * 8,
                            dst + i * 2048 + tid * 8);
        }

        #pragma unroll
        for (int cf = 0; cf < 2; ++cf) {             // 16 codes per cfrag
            const int rowB = cf * 16 + lr;
            f16x8 bh0 = *reinterpret_cast<const f16x8*>(&eb[swz(rowB, lk * 8)]);
            f16x8 bh1 = *reinterpret_cast<const f16x8*>(&eb[swz(rowB, 32 + lk * 8)]);
            f16x8 bl0 = *reinterpret_cast<const f16x8*>(&eb[swz(rowB, 64 + lk * 8)]);
            f16x8 bl1 = *reinterpret_cast<const f16x8*>(&eb[swz(rowB, 96 + lk * 8)]);
            const int codeg = ch * 32 + cf * 16 + lr;
            const float e2v = e2s[codeg];
            #pragma unroll
            for (int s = 0; s < 2; ++s) {
                f32x4 acc = (f32x4){0.f, 0.f, 0.f, 0.f};
                acc = __builtin_amdgcn_mfma_f32_16x16x32_f16(ah[s][0], bh0, acc, 0, 0, 0);
                acc = __builtin_amdgcn_mfma_f32_16x16x32_f16(ah[s][1], bh1, acc, 0, 0, 0);
                acc = __builtin_amdgcn_mfma_f32_16x16x32_f16(ah[s][0], bl0, acc, 0, 0, 0);
                acc = __builtin_amdgcn_mfma_f32_16x16x32_f16(ah[s][1], bl1, acc, 0, 0, 0);
                acc = __builtin_amdgcn_mfma_f32_16x16x32_f16(al[s][0], bh0, acc, 0, 0, 0);
                acc = __builtin_amdgcn_mfma_f32_16x16x32_f16(al[s][1], bh1, acc, 0, 0, 0);
                #pragma unroll
                for (int r = 0; r < 4; ++r) {
                    float vd = fmaf(-2.0f, acc[r], e2v);
                    const int si = s * 4 + r;
                    if (vd < bestv[si]) { bestv[si] = vd; besti[si] = codeg; }
                }
            }
        }

        // counted-wait barrier: next chunk's loads must be done; the chunk-after's
        // 2 loads stay in flight across the barrier (never drain to 0 mid-loop).
        if (ch < 15) {
            if (ch < 14) {
                asm volatile("s_waitcnt vmcnt(2)" ::: "memory");
            } else {
                asm volatile("s_waitcnt vmcnt(0)" ::: "memory");
            }
            __builtin_amdgcn_sched_barrier(0);
            __builtin_amdgcn_s_barrier();
            __builtin_amdgcn_sched_barrier(0);
        }
    }

    // ---- in-wave argmin reduce over the 16 code-columns ----
    #pragma unroll
    for (int si = 0; si < 8; ++si) {
        float v = bestv[si]; int i = besti[si];
        #pragma unroll
        for (int m = 1; m < 16; m <<= 1) {
            float v2 = __shfl_xor(v, m, 64);
            int   i2 = __shfl_xor(i, m, 64);
            if (v2 < v || (v2 == v && i2 < i)) { v = v2; i = i2; }
        }
        bestv[si] = v; besti[si] = i;
    }
    if (lr == 0) {
        #pragma unroll
        for (int s = 0; s < 2; ++s)
            #pragma unroll
            for (int r = 0; r < 4; ++r)
                kbs[wid * 32 + s * 16 + lk * 4 + r] = besti[s * 4 + r];  // C/D row map
    }
    __syncthreads();

    // ---- epilogue: scatter-read embt row, coalesced d-major stores ----
    {
        const int c_ = tid & 127;
        const int dh = tid >> 7;                     // d half (32 each)
        const int k  = kbs[c_];
        const float* qrow = embt + k * 64 + dh * 32; // L2-resident
        float* op = out + xslab + (size_t)(dh * 32) * 256 + chalf * 128 + c_;
        #pragma unroll
        for (int q4 = 0; q4 < 8; ++q4) {
            f32x4 qq = *reinterpret_cast<const f32x4*>(&qrow[q4 * 4]);
            #pragma unroll
            for (int j = 0; j < 4; ++j)
                op[(q4 * 4 + j) * 256] = qq[j];
        }
    }
    if (tid < 128)
        outIdx[(size_t)(b * 256 + chalf * 128 + tid) * 16 + g] = (float)kbs[tid];
}

// ---------------- fallback (ws too small): R5-style self-contained -------------
__global__ __launch_bounds__(512, 2)
void vq_fallback(const float* __restrict__ x, const float* __restrict__ meanp,
                 const float* __restrict__ sdp, const float* __restrict__ emb,
                 float* __restrict__ out, float* __restrict__ outIdx)
{
    __shared__ __align__(16) f16 xa[128 * 128];
    __shared__ __align__(16) f16 es2[128 * 128];
    __shared__ float e2s[512];
    __shared__ float red_v[4][128];
    __shared__ int   red_i[4][128];
    __shared__ int   kb[128];

    const int tid  = threadIdx.x;
    const int lane = tid & 63;
    const int wid  = tid >> 6;
    const int wr   = wid >> 2;
    const int wc   = wid & 3;
    const int lr   = lane & 15;
    const int lk   = lane >> 4;

    const int blk   = blockIdx.x;
    const int chalf = blk & 1;
    const int g     = (blk >> 1) & 15;
    const int b     = blk >> 5;

    const float mean = meanp[0];
    const float sd   = sdp[0];
    const bool  sdz  = (sd == 0.0f);
    const float safe = sdz ? 1.0f : sd;

    const int xbase = b * 262144 + g * 16384 + chalf * 128;

    {
        const int c_ = tid & 127;
        const int dq = tid >> 7;
        const float* src = x + xbase + c_;
        #pragma unroll
        for (int jv = 0; jv < 2; ++jv) {
            f16x8 hi, lo;
            #pragma unroll
            for (int e = 0; e < 8; ++e) {
                int d = dq * 16 + jv * 8 + e;
                float v = src[d * 256];
                float s = (sdz ? 0.0f : v / safe) - mean;
                f16 h = (f16)s;
                hi[e] = h;
                lo[e] = (f16)(s - (float)h);
            }
            *reinterpret_cast<f16x8*>(&xa[swz(c_, dq * 16 + jv * 8)])      = hi;
            *reinterpret_cast<f16x8*>(&xa[swz(c_, 64 + dq * 16 + jv * 8)]) = lo;
        }
    }
    {
        float s = 0.0f;
        for (int d = 0; d < 64; ++d) {
            float v = emb[d * 512 + tid];
            s = fmaf(v, v, s);
        }
        e2s[tid] = s;
    }

    float bestv[16];
    int   besti[16];
    #pragma unroll
    for (int s = 0; s < 16; ++s) { bestv[s] = FLTMAX; besti[s] = 0; }

    for (int ch = 0; ch < 4; ++ch) {
        __syncthreads();
        {
            const int cl = tid & 127;
            const int dq = tid >> 7;
            const float* srcE = emb + ch * 128 + cl;
            #pragma unroll
            for (int jv = 0; jv < 2; ++jv) {
                f16x8 hi, lo;
                #pragma unroll
                for (int e = 0; e < 8; ++e) {
                    int d = dq * 16 + jv * 8 + e;
                    float v = srcE[d * 512];
                    f16 h = (f16)v;
                    hi[e] = h;
                    lo[e] = (f16)(v - (float)h);
                }
                *reinterpret_cast<f16x8*>(&es2[swz(cl, dq * 16 + jv * 8)])      = hi;
                *reinterpret_cast<f16x8*>(&es2[swz(cl, 64 + dq * 16 + jv * 8)]) = lo;
            }
        }
        __syncthreads();

        f32x4 acc[4][2];
        #pragma unroll
        for (int fi = 0; fi < 4; ++fi)
            #pragma unroll
            for (int fj = 0; fj < 2; ++fj)
                acc[fi][fj] = (f32x4){0.f, 0.f, 0.f, 0.f};

        #pragma unroll
        for (int t = 0; t < 3; ++t) {
            const int ah2 = (t == 2) ? 1 : 0;
            const int eh2 = (t == 1) ? 1 : 0;
            #pragma unroll
            for (int dh2 = 0; dh2 < 2; ++dh2) {
                const int kB = eh2 * 64 + dh2 * 32 + lk * 8;
                const int kA = ah2 * 64 + dh2 * 32 + lk * 8;
                f16x8 bf[2], af[4];
                #pragma unroll
                for (int fj = 0; fj < 2; ++fj)
                    bf[fj] = *reinterpret_cast<const f16x8*>(
                        &es2[swz(wc * 32 + fj * 16 + lr, kB)]);
                #pragma unroll
                for (int fi = 0; fi < 4; ++fi)
                    af[fi] = *reinterpret_cast<const f16x8*>(
                        &xa[swz(wr * 64 + fi * 16 + lr, kA)]);
                #pragma unroll
                for (int fi = 0; fi < 4; ++fi)
                    #pragma unroll
                    for (int fj = 0; fj < 2; ++fj)
                        acc[fi][fj] = __builtin_amdgcn_mfma_f32_16x16x32_f16(
                            af[fi], bf[fj], acc[fi][fj], 0, 0, 0);
            }
        }

        #pragma unroll
        for (int fj = 0; fj < 2; ++fj) {
            const int codeg = ch * 128 + wc * 32 + fj * 16 + lr;
            const float e2v = e2s[codeg];
            #pragma unroll
            for (int fi = 0; fi < 4; ++fi)
                #pragma unroll
                for (int r = 0; r < 4; ++r) {
                    float vd = fmaf(-2.0f, acc[fi][fj][r], e2v);
                    const int s = fi * 4 + r;
                    if (vd < bestv[s]) { bestv[s] = vd; besti[s] = codeg; }
                }
        }
    }

    #pragma unroll
    for (int s = 0; s < 16; ++s) {
        float v = bestv[s]; int i = besti[s];
        #pragma unroll
        for (int m = 1; m < 16; m <<= 1) {
            float v2 = __shfl_xor(v, m, 64);
            int   i2 = __shfl_xor(i, m, 64);
            if (v2 < v || (v2 == v && i2 < i)) { v = v2; i = i2; }
        }
        bestv[s] = v; besti[s] = i;
    }
    if (lr == 0) {
        #pragma unroll
        for (int fi = 0; fi < 4; ++fi)
            #pragma unroll
            for (int r = 0; r < 4; ++r) {
                int row = wr * 64 + fi * 16 + lk * 4 + r;
                red_v[wc][row] = bestv[fi * 4 + r];
                red_i[wc][row] = besti[fi * 4 + r];
            }
    }
    __syncthreads();
    if (tid < 128) {
        float bv = red_v[0][tid]; int bi = red_i[0][tid];
        #pragma unroll
        for (int w2 = 1; w2 < 4; ++w2) {
            float v = red_v[w2][tid]; int i = red_i[w2][tid];
            if (v < bv || (v == bv && i < bi)) { bv = v; bi = i; }
        }
        kb[tid] = bi;
    }
    __syncthreads();

    float* out_ = out + xbase;
    #pragma unroll 4
    for (int i = 0; i < 16; ++i) {
        int lin = i * 512 + tid;
        int c_  = lin & 127;
        int d   = lin >> 7;
        float q = emb[d * 512 + kb[c_]];
        out_[d * 256 + c_] = (q + mean) * sd;
    }
    if (tid < 128) {
        int n = (b * 256 + chalf * 128 + tid) * 16 + g;
        outIdx[n] = (float)kb[tid];
    }
}

extern "C" void kernel_launch(void* const* d_in, const int* in_sizes, int n_in,
                              void* d_out, int out_size, void* d_ws, size_t ws_size,
                              hipStream_t stream) {
    const float* x    = (const float*)d_in[0];
    const float* mean = (const float*)d_in[1];
    const float* sd   = (const float*)d_in[2];
    const float* emb  = (const float*)d_in[3];
    float* out    = (float*)d_out;
    float* outIdx = out + NELEM0;

    if (ws_size >= (size_t)WS_NEED) {
        f16*   ecvt = (f16*)d_ws;
        float* e2p  = (float*)((char*)d_ws + 131072);
        float* embt = (float*)((char*)d_ws + 139264);
        prep_kernel<<<dim3(8), dim3(256), 0, stream>>>(emb, mean, sd, ecvt, e2p, embt);
        vq_main<<<dim3(1024), dim3(256), 0, stream>>>(x, mean, sd, ecvt, e2p, embt, out, outIdx);
    } else {
        vq_fallback<<<dim3(1024), dim3(512), 0, stream>>>(x, mean, sd, emb, out, outIdx);
    }
}